// Round 2
// baseline (564.318 us; speedup 1.0000x reference)
//
#include <hip/hip_runtime.h>
#include <hip/hip_bf16.h>

typedef __hip_bfloat16 bf16;
typedef unsigned short u16;
typedef __attribute__((ext_vector_type(8))) short s16x8;
typedef __attribute__((ext_vector_type(4))) float f32x4;

#define CIN 256
#define COUT 256
#define NPIX 3136      // 56*56
#define TAPS10 10      // 9 real taps + 1 zero pad (for K=2taps*16ci MFMA pairing)
#define PADS 24        // elems per (row,col) site in xs: 16 ci + 8 pad (16B align + bank spread)
#define OSTRIDE 168    // elems per cout in as: 10*16 + 8 pad

__device__ __forceinline__ u16 f2b(float f) {   // f32 -> bf16 bits, round-nearest-even
  union { float f; unsigned u; } c; c.f = f;
  unsigned r = (c.u + 0x7FFFu + ((c.u >> 16) & 1u)) >> 16;
  return (u16)r;
}

// ---------------- K1: global average pool  (b,c) -> pooled[b*256+c] ----------------
__global__ void gap_kernel(const float* __restrict__ x, float* __restrict__ pooled) {
  int bc = blockIdx.x;                       // b*256 + c, 4096 blocks
  const float* p = x + (size_t)bc * NPIX;
  float s = 0.f;
  for (int i = threadIdx.x; i < NPIX; i += 256) s += p[i];
  for (int off = 32; off > 0; off >>= 1) s += __shfl_down(s, off, 64);
  __shared__ float red[4];
  if ((threadIdx.x & 63) == 0) red[threadIdx.x >> 6] = s;
  __syncthreads();
  if (threadIdx.x == 0)
    pooled[bc] = (red[0] + red[1] + red[2] + red[3]) * (1.f / 3136.f);
}

// ---------------- K2: routing r[b][e] = sigmoid(pooled[b]·rw[e] + rb[e]) ----------------
__global__ void routing_kernel(const float* __restrict__ pooled, const float* __restrict__ rw,
                               const float* __restrict__ rb, float* __restrict__ r) {
  int t = threadIdx.x;                        // 128 = 16 b * 8 e
  int b = t >> 3, e = t & 7;
  float s = rb[e];
  const float* pb = pooled + b * CIN;
  const float* we = rw + e * CIN;
  for (int c = 0; c < CIN; ++c) s += pb[c] * we[c];
  r[t] = 1.f / (1.f + __expf(-s));
}

// ---------------- K3: combine cw[b][o][t(10)][ci] = bf16( sum_e r[b,e]*W[e,o,ci,t] ) ----------------
__global__ void combine_kernel(const float* __restrict__ W, const float* __restrict__ r,
                               bf16* __restrict__ cw) {
  int o = blockIdx.x, tid = threadIdx.x;      // 256 blocks, 256 threads
  __shared__ float Ws[8 * 2304];              // 73.7 KB
  __shared__ float rs[128];
  for (int e = 0; e < 8; ++e)
    for (int j = tid; j < 2304; j += 256)
      Ws[e * 2304 + j] = W[((size_t)(e * COUT + o)) * 2304 + j];
  if (tid < 128) rs[tid] = r[tid];
  __syncthreads();
  int ci = tid;
  for (int b = 0; b < 16; ++b) {
    float r0 = rs[b*8+0], r1 = rs[b*8+1], r2 = rs[b*8+2], r3 = rs[b*8+3];
    float r4 = rs[b*8+4], r5 = rs[b*8+5], r6 = rs[b*8+6], r7 = rs[b*8+7];
    bf16* dst = cw + ((size_t)(b * COUT + o)) * (TAPS10 * CIN);
    for (int t = 0; t < 9; ++t) {
      const float* w = &Ws[ci * 9 + t];
      float a = r0 * w[0*2304] + r1 * w[1*2304] + r2 * w[2*2304] + r3 * w[3*2304]
              + r4 * w[4*2304] + r5 * w[5*2304] + r6 * w[6*2304] + r7 * w[7*2304];
      dst[t * CIN + ci] = __float2bfloat16(a);
    }
    dst[9 * CIN + ci] = __float2bfloat16(0.f);   // zero tap pad
  }
}

// ---------------- K4: per-sample conv (implicit GEMM, MFMA 16x16x32 bf16) + BN + SiLU ----------------
// Block: (h-tile of 4 rows, o-tile of 64, sample). 2 waves; wave w handles rows h0+2w..h0+2w+1.
// Wave register tile: 4 msub (64 couts) x 7 nsub (112 pixels). K = 2 taps * 16 ci per MFMA.
__global__ __launch_bounds__(128, 2)
void conv_kernel(const float* __restrict__ x, const u16* __restrict__ cw,
                 const float* __restrict__ bng, const float* __restrict__ bnb,
                 const float* __restrict__ bnm, const float* __restrict__ bnv,
                 float* __restrict__ out) {
  const int b = blockIdx.z, o0 = blockIdx.y * 64, h0 = blockIdx.x * 4;
  const int tid = threadIdx.x;
  const int wv = tid >> 6, lane = tid & 63, quad = lane >> 4, ln = lane & 15;

  // xs: 6 rows x 58 cols (zero-padded halo) x 16 ci (bf16 bits), ci innermost.
  __shared__ __align__(16) u16 xs[348 * PADS];       // 16.7 KB
  // as: 64 couts x (10 taps x 16 ci) + pad.
  __shared__ __align__(16) u16 as[64 * OSTRIDE];     // 21.5 KB

  f32x4 acc[4][7];
#pragma unroll
  for (int ms = 0; ms < 4; ++ms)
#pragma unroll
    for (int ns = 0; ns < 7; ++ns) acc[ms][ns] = (f32x4){0.f, 0.f, 0.f, 0.f};

  int bsite[7];   // elem offset of (dy=0,dx=0) site for this lane's pixel, per nsub
#pragma unroll
  for (int ns = 0; ns < 7; ++ns) {
    int pi = ns * 16 + ln;              // 0..111 within the wave's 2 rows
    int hr = (pi >= 56) ? 1 : 0;
    int wc = pi - hr * 56;
    bsite[ns] = ((wv * 2 + hr) * 58 + wc) * PADS;
  }

  const float* xb = x + (size_t)b * CIN * NPIX;
  const u16* cwb = cw + (size_t)(b * COUT + o0) * (TAPS10 * CIN);

  const int su = tid & 63;            // staging: u (col) index, lanes consecutive -> coalesced
  const int sgrp = tid >> 6;
  const int gc = su - 1;
  const bool okc = (gc >= 0) && (gc < 56);

  for (int ck = 0; ck < 16; ++ck) {
    const int ci0 = ck * 16;
    __syncthreads();
    // ---- stage x tile (transpose w-innermost -> ci-innermost, f32 -> bf16), zero halo ----
    if (su < 58) {
      for (int j = sgrp; j < 96; j += 2) {     // j = s*16 + ci
        int s = j >> 4, ci = j & 15;
        int gr = h0 - 1 + s;
        u16 v = 0;
        if (okc && ((unsigned)gr < 56u))
          v = f2b(xb[(size_t)(ci0 + ci) * NPIX + gr * 56 + gc]);
        xs[(s * 58 + su) * PADS + ci] = v;
      }
    }
    // ---- stage A tile: 64 o x 10 t x 16 ci as 16B copies (cw already bf16) ----
    for (int i = tid; i < 1280; i += 128) {
      int o = i / 20, rest = i - o * 20, t = rest >> 1, hf = rest & 1;
      const u16* src = cwb + (size_t)o * (TAPS10 * CIN) + t * CIN + ci0 + hf * 8;
      *(uint4*)&as[o * OSTRIDE + t * 16 + hf * 8] = *(const uint4*)src;
    }
    __syncthreads();
    // ---- MFMA: 5 tap-pairs x (4 a-frags + 7 b-frags -> 28 MFMAs) ----
#pragma unroll
    for (int tp = 0; tp < 5; ++tp) {
      int t = tp * 2 + (quad >> 1);             // this quad's tap within the pair
      int dy, dx;
      if (t < 9) { dy = t / 3; dx = t - dy * 3; } else { dy = 1; dx = 1; }  // t=9: zero weights
      const int boff = (dy * 58 + dx) * PADS + (quad & 1) * 8;
      s16x8 af[4];
#pragma unroll
      for (int ms = 0; ms < 4; ++ms)
        af[ms] = *(const s16x8*)&as[(ms * 16 + ln) * OSTRIDE + tp * 32 + quad * 8];
#pragma unroll
      for (int ns = 0; ns < 7; ++ns) {
        s16x8 bfr = *(const s16x8*)&xs[bsite[ns] + boff];
#pragma unroll
        for (int ms = 0; ms < 4; ++ms)
          acc[ms][ns] = __builtin_amdgcn_mfma_f32_16x16x32_bf16(af[ms], bfr, acc[ms][ns], 0, 0, 0);
      }
    }
  }

  // ---- epilogue: BN (inference) + SiLU, f32 store ----
#pragma unroll
  for (int ms = 0; ms < 4; ++ms) {
#pragma unroll
    for (int rr = 0; rr < 4; ++rr) {
      int o = o0 + ms * 16 + quad * 4 + rr;     // C/D: row = quad*4 + reg
      float inv = bng[o] * rsqrtf(bnv[o] + 1e-5f);
      float bias = bnb[o] - bnm[o] * inv;
      float* ob = out + ((size_t)(b * COUT + o)) * NPIX;
#pragma unroll
      for (int ns = 0; ns < 7; ++ns) {
        int pi = ns * 16 + ln;                  // C/D: col = lane&15
        int hr = (pi >= 56) ? 1 : 0;
        int wc = pi - hr * 56;
        int hg = h0 + wv * 2 + hr;
        float v = acc[ms][ns][rr] * inv + bias;
        v = v / (1.f + __expf(-v));             // SiLU
        ob[hg * 56 + wc] = v;
      }
    }
  }
}

extern "C" void kernel_launch(void* const* d_in, const int* in_sizes, int n_in,
                              void* d_out, int out_size, void* d_ws, size_t ws_size,
                              hipStream_t stream) {
  const float* x   = (const float*)d_in[0];
  const float* rw  = (const float*)d_in[1];
  const float* rb  = (const float*)d_in[2];
  const float* W   = (const float*)d_in[3];
  const float* bng = (const float*)d_in[4];
  const float* bnb = (const float*)d_in[5];
  const float* bnm = (const float*)d_in[6];
  const float* bnv = (const float*)d_in[7];
  float* out = (float*)d_out;

  char* wsb = (char*)d_ws;
  bf16* cw      = (bf16*)wsb;                              // 16*256*10*256*2 = 20,971,520 B
  float* pooled = (float*)(wsb + 20971520);                // 16 KB
  float* r      = (float*)(wsb + 20971520 + 16384);        // 512 B

  gap_kernel<<<4096, 256, 0, stream>>>(x, pooled);
  routing_kernel<<<1, 128, 0, stream>>>(pooled, rw, rb, r);
  combine_kernel<<<256, 256, 0, stream>>>(W, r, cw);
  conv_kernel<<<dim3(14, 4, 16), 128, 0, stream>>>(x, (const u16*)cw,
                                                   bng, bnb, bnm, bnv, out);
}

// Round 3
// 371.331 us; speedup vs baseline: 1.5197x; 1.5197x over previous
//
#include <hip/hip_runtime.h>
#include <hip/hip_bf16.h>

typedef __hip_bfloat16 bf16;
typedef unsigned short u16;
typedef __attribute__((ext_vector_type(8))) short s16x8;
typedef __attribute__((ext_vector_type(4))) float f32x4;
typedef __attribute__((address_space(3))) u16 lds_u16;
typedef __attribute__((address_space(1))) const u16 g_u16;

#define CIN 256
#define COUT 256
#define NPIX 3136      // 56*56
// xq layout: [b][ck(16)][h'(58)][w'(58)][ci(16)] bf16, halo rows/cols zero. row = 928 elems.
// cw layout: [b][ck(16)][o(256)][t(10)][ci(16)] bf16, t=9 is zero pad. per-o block = 160 elems.

__device__ __forceinline__ u16 f2b(float f) {   // f32 -> bf16 bits, round-nearest-even
  union { float f; unsigned u; } c; c.f = f;
  unsigned r = (c.u + 0x7FFFu + ((c.u >> 16) & 1u)) >> 16;
  return (u16)r;
}

// ---------------- K0: transpose x -> xq (bf16, ci-innermost, halo-padded) + fused GAP ----------------
// grid (58, 16, 16) = (h', ck, b), block 256. pooled must be zeroed before launch (holds raw sums).
__global__ __launch_bounds__(256)
void transpose_gap_kernel(const float* __restrict__ x, u16* __restrict__ xq,
                          float* __restrict__ pooled) {
  const int hp = blockIdx.x, ck = blockIdx.y, b = blockIdx.z;
  const int tid = threadIdx.x;
  const int wl = tid & 63, cg = tid >> 6;          // wave cg covers ci = cg*4 .. cg*4+3
  __shared__ __align__(16) u16 row[58 * 16];
  const int gr = hp - 1;
  const bool rowOK = ((unsigned)gr < 56u);
  float v[4];
  const size_t base = ((size_t)b * CIN + ck * 16 + cg * 4) * NPIX + (size_t)(rowOK ? gr : 0) * 56;
#pragma unroll
  for (int i = 0; i < 4; ++i) {
    float f = 0.f;
    if (rowOK && wl < 56) f = x[base + (size_t)i * NPIX + wl];
    v[i] = f;
    if (wl < 56)       row[(wl + 1) * 16 + cg * 4 + i] = f2b(f);
    else if (wl == 56) row[0 * 16 + cg * 4 + i] = 0;
    else if (wl == 57) row[57 * 16 + cg * 4 + i] = 0;
  }
  if (rowOK) {       // GAP partials: all 64 lanes of this wave share the same 4 ci's
#pragma unroll
    for (int i = 0; i < 4; ++i) {
      float s = v[i];
      for (int off = 32; off > 0; off >>= 1) s += __shfl_down(s, off, 64);
      if (wl == 0) atomicAdd(&pooled[b * CIN + ck * 16 + cg * 4 + i], s);
    }
  }
  __syncthreads();
  uint4* dst = (uint4*)(xq + ((size_t)(b * 16 + ck) * 58 + hp) * 928);
  if (tid < 116) dst[tid] = ((const uint4*)row)[tid];
}

// ---------------- K2: routing r[b][e] = sigmoid(mean(pooled)·rw[e] + rb[e]) ----------------
__global__ void routing_kernel(const float* __restrict__ pooled, const float* __restrict__ rw,
                               const float* __restrict__ rb, float* __restrict__ r) {
  int t = threadIdx.x;                        // 128 = 16 b * 8 e
  int b = t >> 3, e = t & 7;
  float s = rb[e];
  const float* pb = pooled + b * CIN;
  const float* we = rw + e * CIN;
  for (int c = 0; c < CIN; ++c) s += (pb[c] * (1.f / 3136.f)) * we[c];
  r[t] = 1.f / (1.f + __expf(-s));
}

// ---------------- K3: combine cw[b][ck][o][t][ci16] = bf16( sum_e r[b,e]*W[e,o,ci,t] ) ----------------
__global__ void combine_kernel(const float* __restrict__ W, const float* __restrict__ r,
                               u16* __restrict__ cw) {
  int o = blockIdx.x, tid = threadIdx.x;      // 256 blocks, 256 threads
  __shared__ float Ws[8 * 2304];              // 73.7 KB
  __shared__ float rs[128];
  for (int e = 0; e < 8; ++e)
    for (int j = tid; j < 2304; j += 256)
      Ws[e * 2304 + j] = W[((size_t)(e * COUT + o)) * 2304 + j];
  if (tid < 128) rs[tid] = r[tid];
  __syncthreads();
  int ci = tid;
  const int ck = ci >> 4, cl = ci & 15;
  for (int b = 0; b < 16; ++b) {
    float r0 = rs[b*8+0], r1 = rs[b*8+1], r2 = rs[b*8+2], r3 = rs[b*8+3];
    float r4 = rs[b*8+4], r5 = rs[b*8+5], r6 = rs[b*8+6], r7 = rs[b*8+7];
    u16* dst = cw + ((size_t)(b * 16 + ck) * COUT + o) * 160 + cl;
    for (int t = 0; t < 9; ++t) {
      const float* w = &Ws[ci * 9 + t];
      float a = r0 * w[0*2304] + r1 * w[1*2304] + r2 * w[2*2304] + r3 * w[3*2304]
              + r4 * w[4*2304] + r5 * w[5*2304] + r6 * w[6*2304] + r7 * w[7*2304];
      dst[t * 16] = f2b(a);
    }
    dst[9 * 16] = 0;                          // zero tap pad
  }
}

// ---------------- K4: per-sample conv (implicit GEMM, MFMA 16x16x32 bf16) + BN + SiLU ----------------
// Block: 256 thr = 4 waves. Tile: 8 rows x 64 couts. Wave wv: rows h0+2wv..+1, 4 msub x 7 nsub accs.
// K = 2 taps * 16 ci per MFMA; 16 ci-chunk iterations. All staging via global_load_lds width-16.
__global__ __launch_bounds__(256)
void conv_kernel(const u16* __restrict__ xq, const u16* __restrict__ cw,
                 const float* __restrict__ bng, const float* __restrict__ bnb,
                 const float* __restrict__ bnm, const float* __restrict__ bnv,
                 float* __restrict__ out) {
  const int b = blockIdx.z, o0 = blockIdx.y * 64, h0 = blockIdx.x * 8;
  const int tid = threadIdx.x;
  const int wv = tid >> 6, lane = tid & 63, quad = lane >> 4, ln = lane & 15;

  // xs: 10 rows x 58 sites x 16 ci, contiguous (= xq layout). 18,560 B used, padded to 19,456.
  __shared__ __align__(16) u16 xs[19 * 512];         // 19,456 B
  // as: 64 couts x 160 (10 taps x 16 ci), contiguous (= cw layout). 20,480 B.
  __shared__ __align__(16) u16 as[64 * 160];
  // total 39,936 B

  f32x4 acc[4][7];
#pragma unroll
  for (int ms = 0; ms < 4; ++ms)
#pragma unroll
    for (int ns = 0; ns < 7; ++ns) acc[ms][ns] = (f32x4){0.f, 0.f, 0.f, 0.f};

  int bsite[7];   // elem offset of (dy=0,dx=0) site for this lane's pixel
#pragma unroll
  for (int ns = 0; ns < 7; ++ns) {
    int pi = ns * 16 + ln;              // 0..111 within the wave's 2 rows
    int hr = (pi >= 56) ? 1 : 0;
    int wc = pi - hr * 56;
    bsite[ns] = ((2 * wv + hr) * 58 + wc) * 16;
  }

  for (int ck = 0; ck < 16; ++ck) {
    const u16* xsrc = xq + ((size_t)(b * 16 + ck) * 58 + h0) * 928;   // 10 rows contiguous
    const u16* asrc = cw + ((size_t)(b * 16 + ck) * COUT + o0) * 160; // 64 o's contiguous
    __syncthreads();                       // previous iter's consumers done
    // ---- stage: 19 x-groups + 20 a-groups of 1024 B, round-robin over 4 waves ----
    for (int g = wv; g < 39; g += 4) {
      if (g < 19)
        __builtin_amdgcn_global_load_lds((g_u16*)(xsrc + g * 512 + lane * 8),
                                         (lds_u16*)(xs + g * 512), 16, 0, 0);
      else
        __builtin_amdgcn_global_load_lds((g_u16*)(asrc + (g - 19) * 512 + lane * 8),
                                         (lds_u16*)(as + (g - 19) * 512), 16, 0, 0);
    }
    __syncthreads();                       // drains vmcnt before barrier
    // ---- MFMA: 5 tap-pairs x (4 a-frags, 7 b-frags -> 28 MFMAs) ----
#pragma unroll
    for (int tp = 0; tp < 5; ++tp) {
      int t = tp * 2 + (quad >> 1);        // this quad's tap within the pair
      int dy, dx;
      if (t < 9) { dy = t / 3; dx = t - dy * 3; } else { dy = 1; dx = 1; }  // t=9: zero weights
      const int boff = (dy * 58 + dx) * 16 + (quad & 1) * 8;
      s16x8 af[4];
#pragma unroll
      for (int ms = 0; ms < 4; ++ms)
        af[ms] = *(const s16x8*)&as[(ms * 16 + ln) * 160 + tp * 32 + quad * 8];
#pragma unroll
      for (int ns = 0; ns < 7; ++ns) {
        s16x8 bfr = *(const s16x8*)&xs[bsite[ns] + boff];
#pragma unroll
        for (int ms = 0; ms < 4; ++ms)
          acc[ms][ns] = __builtin_amdgcn_mfma_f32_16x16x32_bf16(af[ms], bfr, acc[ms][ns], 0, 0, 0);
      }
    }
  }

  // ---- epilogue: BN (inference) + SiLU, f32 store ----
#pragma unroll
  for (int ms = 0; ms < 4; ++ms) {
#pragma unroll
    for (int rr = 0; rr < 4; ++rr) {
      int o = o0 + ms * 16 + quad * 4 + rr;     // C/D: row = quad*4 + reg
      float inv = bng[o] * rsqrtf(bnv[o] + 1e-5f);
      float bias = bnb[o] - bnm[o] * inv;
      float* ob = out + ((size_t)(b * COUT + o)) * NPIX;
#pragma unroll
      for (int ns = 0; ns < 7; ++ns) {
        int pi = ns * 16 + ln;                  // C/D: col = lane&15
        int hr = (pi >= 56) ? 1 : 0;
        int wc = pi - hr * 56;
        int hg = h0 + 2 * wv + hr;
        float v = acc[ms][ns][rr] * inv + bias;
        v = v / (1.f + __expf(-v));             // SiLU
        ob[hg * 56 + wc] = v;
      }
    }
  }
}

extern "C" void kernel_launch(void* const* d_in, const int* in_sizes, int n_in,
                              void* d_out, int out_size, void* d_ws, size_t ws_size,
                              hipStream_t stream) {
  const float* x   = (const float*)d_in[0];
  const float* rw  = (const float*)d_in[1];
  const float* rb  = (const float*)d_in[2];
  const float* W   = (const float*)d_in[3];
  const float* bng = (const float*)d_in[4];
  const float* bnb = (const float*)d_in[5];
  const float* bnm = (const float*)d_in[6];
  const float* bnv = (const float*)d_in[7];
  float* out = (float*)d_out;

  char* wsb = (char*)d_ws;
  u16*  cw     = (u16*)wsb;                          // 16*16*256*160*2      = 20,971,520 B
  u16*  xq     = (u16*)(wsb + 20971520);             // 16*16*58*58*16*2+1K  = 27,554,816 B
  float* pooled = (float*)(wsb + 20971520 + 27554816); // 16,384 B
  float* r      = (float*)(wsb + 20971520 + 27554816 + 16384); // 512 B

  hipMemsetAsync(pooled, 0, 16 * CIN * sizeof(float), stream);
  transpose_gap_kernel<<<dim3(58, 16, 16), 256, 0, stream>>>(x, xq, pooled);
  routing_kernel<<<1, 128, 0, stream>>>(pooled, rw, rb, r);
  combine_kernel<<<256, 256, 0, stream>>>(W, r, cw);
  conv_kernel<<<dim3(7, 4, 16), 256, 0, stream>>>(xq, cw, bng, bnb, bnm, bnv, out);
}

// Round 7
// 322.295 us; speedup vs baseline: 1.7509x; 1.1521x over previous
//
#include <hip/hip_runtime.h>
#include <hip/hip_bf16.h>

typedef unsigned short u16;
typedef __attribute__((ext_vector_type(8))) short s16x8;
typedef __attribute__((ext_vector_type(4))) float f32x4;
typedef __attribute__((address_space(3))) u16 lds_u16;
typedef __attribute__((address_space(1))) const u16 g_u16;

#define CIN 256
#define COUT 256
#define NPIX 3136      // 56*56
// xq layout: [b][ck(16)][h'(58)][w'(58)][ci(16)] bf16, halo rows/cols zero. row = 928 elems.
// cw layout: [b][ck(16)][o(256)][t(10)][ci(16)] bf16, t=9 zero pad. per-o block = 160 elems.

__device__ __forceinline__ u16 f2b(float f) {   // f32 -> bf16 bits, RNE
  union { float f; unsigned u; } c; c.f = f;
  unsigned r = (c.u + 0x7FFFu + ((c.u >> 16) & 1u)) >> 16;
  return (u16)r;
}

// ---------------- K0: transpose x -> xq + fused GAP — ROUND-3 VERBATIM (proven) ----------------
// grid (58, 16, 16) = (h', ck, b), block 256. pooled must be zeroed before launch (holds raw sums).
__global__ __launch_bounds__(256)
void transpose_gap_kernel(const float* __restrict__ x, u16* __restrict__ xq,
                          float* __restrict__ pooled) {
  const int hp = blockIdx.x, ck = blockIdx.y, b = blockIdx.z;
  const int tid = threadIdx.x;
  const int wl = tid & 63, cg = tid >> 6;          // wave cg covers ci = cg*4 .. cg*4+3
  __shared__ __align__(16) u16 row[58 * 16];
  const int gr = hp - 1;
  const bool rowOK = ((unsigned)gr < 56u);
  float v[4];
  const size_t base = ((size_t)b * CIN + ck * 16 + cg * 4) * NPIX + (size_t)(rowOK ? gr : 0) * 56;
#pragma unroll
  for (int i = 0; i < 4; ++i) {
    float f = 0.f;
    if (rowOK && wl < 56) f = x[base + (size_t)i * NPIX + wl];
    v[i] = f;
    if (wl < 56)       row[(wl + 1) * 16 + cg * 4 + i] = f2b(f);
    else if (wl == 56) row[0 * 16 + cg * 4 + i] = 0;
    else if (wl == 57) row[57 * 16 + cg * 4 + i] = 0;
  }
  if (rowOK) {       // GAP partials: all 64 lanes of this wave share the same 4 ci's
#pragma unroll
    for (int i = 0; i < 4; ++i) {
      float s = v[i];
      for (int off = 32; off > 0; off >>= 1) s += __shfl_down(s, off, 64);
      if (wl == 0) atomicAdd(&pooled[b * CIN + ck * 16 + cg * 4 + i], s);
    }
  }
  __syncthreads();
  uint4* dst = (uint4*)(xq + ((size_t)(b * 16 + ck) * 58 + hp) * 928);
  if (tid < 116) dst[tid] = ((const uint4*)row)[tid];
}

// ---------------- K3: combine (routing fused) — THE SUSPECT UNDER TEST (unchanged except /3136) --
// grid 256 (one per o), block 256. W held in 72 regs; r computed in-block from pooled SUMS.
__global__ __launch_bounds__(256)
void combine_kernel(const float* __restrict__ W, const float* __restrict__ pooled,
                    const float* __restrict__ rw, const float* __restrict__ rb,
                    u16* __restrict__ cw) {
  const int o = blockIdx.x, tid = threadIdx.x;
  __shared__ float rs[128];
  if (tid < 128) {                       // routing: r[b][e]
    int b = tid >> 3, e = tid & 7;
    float s = rb[e];
    const float* pb = pooled + b * CIN;
    const float* we = rw + e * CIN;
    for (int c = 0; c < CIN; ++c) s += (pb[c] * (1.f / 3136.f)) * we[c];
    rs[tid] = 1.f / (1.f + __expf(-s));
  }
  float wreg[8][9];
#pragma unroll
  for (int e = 0; e < 8; ++e) {
    const float* wp = W + ((size_t)(e * COUT + o)) * 2304 + tid;
#pragma unroll
    for (int k = 0; k < 9; ++k) wreg[e][k] = wp[k * 256];
  }
  int off2[9];                            // store offsets (loop-invariant over b)
#pragma unroll
  for (int k = 0; k < 9; ++k) {
    int j = tid + k * 256, ci = j / 9, t = j - ci * 9;
    off2[k] = ((ci >> 4) * 256 + o) * 160 + t * 16 + (ci & 15);
  }
  const int offz = ((tid >> 4) * 256 + o) * 160 + 144 + (tid & 15);
  __syncthreads();
  for (int b = 0; b < 16; ++b) {
    float rv[8];
#pragma unroll
    for (int e = 0; e < 8; ++e) rv[e] = rs[b * 8 + e];
    u16* dst = cw + (size_t)b * 655360;   // 16*256*160
#pragma unroll
    for (int k = 0; k < 9; ++k) {
      float a = 0.f;
#pragma unroll
      for (int e = 0; e < 8; ++e) a += rv[e] * wreg[e][k];
      dst[off2[k]] = f2b(a);
    }
    dst[offz] = 0;                        // tap-9 zero pad
  }
}

// ---------------- K4: conv — ROUND-3 VERBATIM (proven) ----------------
__global__ __launch_bounds__(256)
void conv_kernel(const u16* __restrict__ xq, const u16* __restrict__ cw,
                 const float* __restrict__ bng, const float* __restrict__ bnb,
                 const float* __restrict__ bnm, const float* __restrict__ bnv,
                 float* __restrict__ out) {
  const int b = blockIdx.z, o0 = blockIdx.y * 64, h0 = blockIdx.x * 8;
  const int tid = threadIdx.x;
  const int wv = tid >> 6, lane = tid & 63, quad = lane >> 4, ln = lane & 15;

  __shared__ __align__(16) u16 xs[19 * 512];         // 19,456 B
  __shared__ __align__(16) u16 as[64 * 160];         // 20,480 B

  f32x4 acc[4][7];
#pragma unroll
  for (int ms = 0; ms < 4; ++ms)
#pragma unroll
    for (int ns = 0; ns < 7; ++ns) acc[ms][ns] = (f32x4){0.f, 0.f, 0.f, 0.f};

  int bsite[7];
#pragma unroll
  for (int ns = 0; ns < 7; ++ns) {
    int pi = ns * 16 + ln;
    int hr = (pi >= 56) ? 1 : 0;
    int wc = pi - hr * 56;
    bsite[ns] = ((2 * wv + hr) * 58 + wc) * 16;
  }

  for (int ck = 0; ck < 16; ++ck) {
    const u16* xsrc = xq + ((size_t)(b * 16 + ck) * 58 + h0) * 928;   // 10 rows contiguous
    const u16* asrc = cw + ((size_t)(b * 16 + ck) * COUT + o0) * 160; // 64 o's contiguous
    __syncthreads();                       // previous iter's consumers done
    for (int g = wv; g < 39; g += 4) {
      if (g < 19)
        __builtin_amdgcn_global_load_lds((g_u16*)(xsrc + g * 512 + lane * 8),
                                         (lds_u16*)(xs + g * 512), 16, 0, 0);
      else
        __builtin_amdgcn_global_load_lds((g_u16*)(asrc + (g - 19) * 512 + lane * 8),
                                         (lds_u16*)(as + (g - 19) * 512), 16, 0, 0);
    }
    __syncthreads();                       // drains vmcnt before barrier
#pragma unroll
    for (int tp = 0; tp < 5; ++tp) {
      int t = tp * 2 + (quad >> 1);
      int dy, dx;
      if (t < 9) { dy = t / 3; dx = t - dy * 3; } else { dy = 1; dx = 1; }  // t=9: zero weights
      const int boff = (dy * 58 + dx) * 16 + (quad & 1) * 8;
      s16x8 af[4];
#pragma unroll
      for (int ms = 0; ms < 4; ++ms)
        af[ms] = *(const s16x8*)&as[(ms * 16 + ln) * 160 + tp * 32 + quad * 8];
#pragma unroll
      for (int ns = 0; ns < 7; ++ns) {
        s16x8 bfr = *(const s16x8*)&xs[bsite[ns] + boff];
#pragma unroll
        for (int ms = 0; ms < 4; ++ms)
          acc[ms][ns] = __builtin_amdgcn_mfma_f32_16x16x32_bf16(af[ms], bfr, acc[ms][ns], 0, 0, 0);
      }
    }
  }

  // ---- epilogue: BN + SiLU, f32 store ----
#pragma unroll
  for (int ms = 0; ms < 4; ++ms) {
#pragma unroll
    for (int rr = 0; rr < 4; ++rr) {
      int o = o0 + ms * 16 + quad * 4 + rr;     // C/D: row = quad*4 + reg
      float inv = bng[o] * rsqrtf(bnv[o] + 1e-5f);
      float bias = bnb[o] - bnm[o] * inv;
      float* ob = out + ((size_t)(b * COUT + o)) * NPIX;
#pragma unroll
      for (int ns = 0; ns < 7; ++ns) {
        int pi = ns * 16 + ln;                  // C/D: col = lane&15
        int hr = (pi >= 56) ? 1 : 0;
        int wc = pi - hr * 56;
        int hg = h0 + 2 * wv + hr;
        float v = acc[ms][ns][rr] * inv + bias;
        v = v / (1.f + __expf(-v));             // SiLU
        ob[hg * 56 + wc] = v;
      }
    }
  }
}

extern "C" void kernel_launch(void* const* d_in, const int* in_sizes, int n_in,
                              void* d_out, int out_size, void* d_ws, size_t ws_size,
                              hipStream_t stream) {
  const float* x   = (const float*)d_in[0];
  const float* rw  = (const float*)d_in[1];
  const float* rb  = (const float*)d_in[2];
  const float* W   = (const float*)d_in[3];
  const float* bng = (const float*)d_in[4];
  const float* bnb = (const float*)d_in[5];
  const float* bnm = (const float*)d_in[6];
  const float* bnv = (const float*)d_in[7];
  float* out = (float*)d_out;

  char* wsb = (char*)d_ws;
  u16*  cw     = (u16*)wsb;                            // 16*16*256*160*2      = 20,971,520 B
  u16*  xq     = (u16*)(wsb + 20971520);               // 16*16*58*58*16*2+1K  = 27,554,816 B
  float* pooled = (float*)(wsb + 20971520 + 27554816); // 16,384 B

  hipMemsetAsync(pooled, 0, 16 * CIN * sizeof(float), stream);
  transpose_gap_kernel<<<dim3(58, 16, 16), 256, 0, stream>>>(x, xq, pooled);
  combine_kernel<<<256, 256, 0, stream>>>(W, pooled, rw, rb, cw);
  conv_kernel<<<dim3(7, 4, 16), 256, 0, stream>>>(xq, cw, bng, bnb, bnm, bnv, out);
}